// Round 4
// baseline (75.877 us; speedup 1.0000x reference)
//
#include <hip/hip_runtime.h>

namespace {
constexpr int kB     = 256;
constexpr int kT     = 336;
constexpr int kC     = 512;
constexpr int kK     = 3;
constexpr int kU     = 16;   // t-rows per chunk; 336 = 21 * 16
constexpr int kWaves = 4;    // 256 threads / 64
}

// One thread per (b,c), sequential scan over t (minimum HBM traffic), but x
// is staged chunk-by-chunk into LDS via async global_load_lds with a counted
// vmcnt(16) pipeline (T3/T4 pattern). Two distinct __shared__ buffers give
// compile-time disambiguation (no alias-forced vmcnt(0)); each wave reads
// only rows it staged itself, so NO __syncthreads anywhere -> the barrier
// drain that would kill the pipeline never exists.
__global__ __launch_bounds__(256) void ema_mix_kernel(
    const float* __restrict__ x,
    const float* __restrict__ logit_alpha,
    const float* __restrict__ mix_logits,
    float* __restrict__ out)
{
    __shared__ float bufA[kWaves][kU][64];   // 16 KB
    __shared__ float bufB[kWaves][kU][64];   // 16 KB

    const int lane = threadIdx.x & 63;
    const int w    = threadIdx.x >> 6;
    const int c    = ((blockIdx.x & 1) << 8) | (w << 6) | lane;
    const int b    = blockIdx.x >> 1;

    // ---- per-(k,c) parameters ----
    float a[kK], oma[kK], inva[kK], mixw[kK];
    {
        float logits[kK];
        float lmax = -3.402823e38f;
        #pragma unroll
        for (int k = 0; k < kK; ++k) {
            logits[k] = mix_logits[c * kK + k];
            lmax = fmaxf(lmax, logits[k]);
        }
        float esum = 0.f;
        #pragma unroll
        for (int k = 0; k < kK; ++k) {
            logits[k] = expf(logits[k] - lmax);
            esum += logits[k];
        }
        const float rs = 1.0f / esum;
        #pragma unroll
        for (int k = 0; k < kK; ++k) {
            mixw[k] = logits[k] * rs;
            const float z = logit_alpha[k * kC + c];
            float s;
            if (z >= 0.f) {
                s = 1.0f / (1.0f + expf(-z));
            } else {
                const float e = expf(z);
                s = e / (1.0f + e);
            }
            s = fminf(fmaxf(s, 1e-4f), (float)(1.0 - 1e-4));
            a[k]    = s;
            oma[k]  = 1.0f - s;
            inva[k] = 1.0f / s;
        }
    }

    const float* xp = x   + (size_t)b * (kT * kC) + c;
    float*       op = out + (size_t)b * (kT * kC) + c;

    float apow[kK], vinv[kK], S[kK];
    #pragma unroll
    for (int k = 0; k < kK; ++k) { apow[k] = 1.f; vinv[k] = 1.f; S[k] = 0.f; }

    // async-stage one 16-row chunk into `buf` (this wave's rows only).
    // LDS dest is wave-uniform base + lane*4 (HW rule) == &buf[w][r][lane].
    auto stage = [&](float (&buf)[kWaves][kU][64], int tc) {
        const float* g = xp + (size_t)tc * kC;
        #pragma unroll
        for (int r = 0; r < kU; ++r) {
            __builtin_amdgcn_global_load_lds(
                (const __attribute__((address_space(1))) void*)(g + (size_t)r * kC),
                (__attribute__((address_space(3))) void*)(&buf[w][r][0]),
                4, 0, 0);
        }
    };

    auto compute = [&](float (&buf)[kWaves][kU][64], int tbase) {
        #pragma unroll
        for (int i = 0; i < kU; ++i) {
            const float xv = buf[w][i][lane];     // ds_read_b32, conflict-free
            const int t = tbase + i;
            float o = 0.f;
            #pragma unroll
            for (int k = 0; k < kK; ++k) {
                const float wt = (t == 0) ? 1.0f : apow[k] * oma[k];
                S[k] = fmaf(xv, wt, S[k]);
                o = fmaf(S[k] * mixw[k], fminf(vinv[k], 1e8f), o);
                apow[k] *= a[k];
                vinv[k] *= inva[k];
            }
            op[(size_t)t * kC] = o;
        }
    };

    // ---- pipelined main loop: 21 chunks, double-buffered, vmcnt(16) ----
    stage(bufA, 0);
    for (int dch = 0; dch < 10; ++dch) {
        const int tc = dch * 32;
        stage(bufB, tc + kU);
        // oldest 16 outstanding = bufA's loads; leave bufB's 16 in flight
        asm volatile("s_waitcnt vmcnt(16)" ::: "memory");
        __builtin_amdgcn_sched_barrier(0);
        compute(bufA, tc);
        stage(bufA, tc + 32);
        asm volatile("s_waitcnt vmcnt(16)" ::: "memory");
        __builtin_amdgcn_sched_barrier(0);
        compute(bufB, tc + kU);
    }
    // epilogue: chunk 20 (tc = 320) sits in bufA; nothing left to prefetch
    asm volatile("s_waitcnt vmcnt(0)" ::: "memory");
    __builtin_amdgcn_sched_barrier(0);
    compute(bufA, 320);
}

extern "C" void kernel_launch(void* const* d_in, const int* in_sizes, int n_in,
                              void* d_out, int out_size, void* d_ws, size_t ws_size,
                              hipStream_t stream) {
    const float* x  = (const float*)d_in[0];
    const float* la = (const float*)d_in[1];
    const float* ml = (const float*)d_in[2];
    float* o = (float*)d_out;

    const int blocks = kB * (kC / 256);  // 512 blocks x 256 threads = one thread per (b,c)
    ema_mix_kernel<<<dim3(blocks), dim3(256), 0, stream>>>(x, la, ml, o);
}

// Round 6
// 58.364 us; speedup vs baseline: 1.3001x; 1.3001x over previous
//
#include <hip/hip_runtime.h>

namespace {
constexpr int kB     = 256;
constexpr int kT     = 336;
constexpr int kC     = 512;
constexpr int kK     = 3;
constexpr int kU     = 16;   // rows per chunk; 336 = 21 * 16
constexpr int kWaves = 4;
}

// One thread per (b,c), single pass (minimum HBM traffic). x staged per-wave
// into double-buffered LDS via async global_load_lds (no register outputs ->
// immune to the R5 register-copy hazard). Counted waits account for the 16
// output stores each compute phase adds to the vmcnt queue:
//   steady queue at wait: [S_{k-2}(16), L_k(16), S_{k-1}(16), L_{k+1}(16)]
//   vmcnt(32) retires exactly [S_{k-2}, L_k]: store-acks have 2 phases of
//   slack (R4 waited on 0-slack stores -> serialized), and L_{k+1}'s 16
//   loads (4 KB/wave) stay in flight across every wait.
// Waves never read another wave's rows -> NO __syncthreads anywhere.
#define WAITV(n) do { asm volatile("s_waitcnt vmcnt(" #n ")" ::: "memory"); \
                      __builtin_amdgcn_sched_barrier(0); } while (0)

__global__ __launch_bounds__(256) void ema_mix_kernel(
    const float* __restrict__ x,
    const float* __restrict__ logit_alpha,
    const float* __restrict__ mix_logits,
    float* __restrict__ out)
{
    __shared__ float bufA[kWaves][kU][64];   // 16 KB
    __shared__ float bufB[kWaves][kU][64];   // 16 KB

    const int lane = threadIdx.x & 63;
    const int w    = threadIdx.x >> 6;
    const int c    = ((blockIdx.x & 1) << 8) | (w << 6) | lane;
    const int b    = blockIdx.x >> 1;

    // ---- per-(k,c) parameters ----
    float a[kK], oma[kK], inva[kK], mixw[kK];
    {
        float logits[kK];
        float lmax = -3.402823e38f;
        #pragma unroll
        for (int k = 0; k < kK; ++k) {
            logits[k] = mix_logits[c * kK + k];
            lmax = fmaxf(lmax, logits[k]);
        }
        float esum = 0.f;
        #pragma unroll
        for (int k = 0; k < kK; ++k) {
            logits[k] = expf(logits[k] - lmax);
            esum += logits[k];
        }
        const float rs = 1.0f / esum;
        #pragma unroll
        for (int k = 0; k < kK; ++k) {
            mixw[k] = logits[k] * rs;
            const float z = logit_alpha[k * kC + c];
            float s;
            if (z >= 0.f) {
                s = 1.0f / (1.0f + expf(-z));
            } else {
                const float e = expf(z);
                s = e / (1.0f + e);
            }
            s = fminf(fmaxf(s, 1e-4f), (float)(1.0 - 1e-4));
            a[k]    = s;
            oma[k]  = 1.0f - s;
            inva[k] = 1.0f / s;
        }
    }

    // drain param loads so the vmcnt queue is empty at pipeline start
    asm volatile("s_waitcnt vmcnt(0)" ::: "memory");
    __builtin_amdgcn_sched_barrier(0);

    const float* xp = x   + (size_t)b * (kT * kC) + c;
    float*       op = out + (size_t)b * (kT * kC) + c;

    float apow[kK], vinv[kK], S[kK];
    #pragma unroll
    for (int k = 0; k < kK; ++k) { apow[k] = 1.f; vinv[k] = 1.f; S[k] = 0.f; }

    auto stage = [&](float (&buf)[kWaves][kU][64], int ch) {
        const float* g = xp + (size_t)ch * (kU * kC);
        #pragma unroll
        for (int r = 0; r < kU; ++r) {
            __builtin_amdgcn_global_load_lds(
                (const __attribute__((address_space(1))) void*)(g + (size_t)r * kC),
                (__attribute__((address_space(3))) void*)(&buf[w][r][0]),
                4, 0, 0);
        }
    };

    auto compute = [&](float (&buf)[kWaves][kU][64], int ch, bool first) {
        const int tbase = ch * kU;
        #pragma unroll
        for (int i = 0; i < kU; ++i) {
            const float xv = buf[w][i][lane];     // ds_read_b32, conflict-free
            float o = 0.f;
            #pragma unroll
            for (int k = 0; k < kK; ++k) {
                const float wt = (first && i == 0) ? 1.0f : apow[k] * oma[k];
                S[k] = fmaf(xv, wt, S[k]);
                o = fmaf(S[k] * mixw[k], fminf(vinv[k], 1e8f), o);
                apow[k] *= a[k];
                vinv[k] *= inva[k];
            }
            __builtin_nontemporal_store(o, &op[(size_t)(tbase + i) * kC]);
        }
    };

    // chunk k lives in buf (k even -> A, k odd -> B); 21 chunks (0..20)
    stage(bufA, 0);
    // phase 0: queue [L0, L1] -> W(16) retires L0
    stage(bufB, 1);  WAITV(16);  compute(bufA, 0, true);
    // phases 1..18 (pairs), steady: W(32) retires [S_{k-2}, L_k]
    #pragma unroll 1
    for (int kk = 1; kk <= 17; kk += 2) {
        stage(bufA, kk + 1);  WAITV(32);  compute(bufB, kk,     false);
        stage(bufB, kk + 2);  WAITV(32);  compute(bufA, kk + 1, false);
    }
    // phase 19: stage last chunk (20 -> A)
    stage(bufA, 20);  WAITV(32);  compute(bufB, 19, false);
    // phase 20: queue [S18, L20, S19] -> W(16) retires [S18, L20]
    WAITV(16);  compute(bufA, 20, false);
}

extern "C" void kernel_launch(void* const* d_in, const int* in_sizes, int n_in,
                              void* d_out, int out_size, void* d_ws, size_t ws_size,
                              hipStream_t stream) {
    const float* x  = (const float*)d_in[0];
    const float* la = (const float*)d_in[1];
    const float* ml = (const float*)d_in[2];
    float* o = (float*)d_out;

    const int blocks = kB * (kC / 256);  // 512 blocks x 256 threads, one thread per (b,c)
    ema_mix_kernel<<<dim3(blocks), dim3(256), 0, stream>>>(x, la, ml, o);
}

// Round 7
// 57.847 us; speedup vs baseline: 1.3117x; 1.0089x over previous
//
#include <hip/hip_runtime.h>

namespace {
constexpr int kB     = 256;
constexpr int kT     = 336;
constexpr int kC     = 512;
constexpr int kK     = 3;
constexpr int kR     = 8;            // rows per chunk; 336 = 42 * 8
constexpr int kNCH   = kT / kR;      // 42 chunks
constexpr int kNB    = 8;            // LDS ring depth (64 KB)
constexpr int kWaves = 4;
}

// One thread per (b,c), single pass (minimum HBM traffic). x staged per-wave
// into an 8-buffer LDS ring via async global_load_lds (16B wide: lane>>4 =
// row, (lane&15)*4 = col-quad -> 2 instrs per 8-row chunk). Prefetch depth 6:
// steady wait vmcnt(58) retires chunk k's 2 loads while chunks k+1..k+5 (10
// instrs) stay in flight, and the newest store group it can drain was issued
// 6 phases earlier -> store-acks never gate (R4/R6's residual stall). Waves
// only read rows they staged -> NO __syncthreads. Wait counts are exact: per
// phase the only vmcnt ops are 2 staged loads + 8 output stores.
#define WAITV(n) do { asm volatile("s_waitcnt vmcnt(" #n ")" ::: "memory"); \
                      __builtin_amdgcn_sched_barrier(0); } while (0)

__global__ __launch_bounds__(256) void ema_mix_kernel(
    const float* __restrict__ x,
    const float* __restrict__ logit_alpha,
    const float* __restrict__ mix_logits,
    float* __restrict__ out)
{
    __shared__ float buf[kNB][kWaves][kR][64];   // 64 KB

    const int lane = threadIdx.x & 63;
    const int w    = threadIdx.x >> 6;
    const int c0w  = ((blockIdx.x & 1) << 8) | (w << 6);
    const int c    = c0w | lane;
    const int b    = blockIdx.x >> 1;

    // ---- per-(k,c) parameters ----
    float a[kK], oma[kK], inva[kK], mixw[kK];
    {
        float logits[kK];
        float lmax = -3.402823e38f;
        #pragma unroll
        for (int k = 0; k < kK; ++k) {
            logits[k] = mix_logits[c * kK + k];
            lmax = fmaxf(lmax, logits[k]);
        }
        float esum = 0.f;
        #pragma unroll
        for (int k = 0; k < kK; ++k) {
            logits[k] = expf(logits[k] - lmax);
            esum += logits[k];
        }
        const float rs = 1.0f / esum;
        #pragma unroll
        for (int k = 0; k < kK; ++k) {
            mixw[k] = logits[k] * rs;
            const float z = logit_alpha[k * kC + c];
            float s;
            if (z >= 0.f) {
                s = 1.0f / (1.0f + expf(-z));
            } else {
                const float e = expf(z);
                s = e / (1.0f + e);
            }
            s = fminf(fmaxf(s, 1e-4f), (float)(1.0 - 1e-4));
            a[k]    = s;
            oma[k]  = 1.0f - s;
            inva[k] = 1.0f / s;
        }
    }

    // drain param loads so the vmcnt queue is empty at pipeline start
    asm volatile("s_waitcnt vmcnt(0)" ::: "memory");
    __builtin_amdgcn_sched_barrier(0);

    const float* xbase = x + (size_t)b * (kT * kC);
    float*       op    = out + (size_t)b * (kT * kC) + c;

    // staging lane mapping (16B-wide global_load_lds):
    const int roff = lane >> 4;             // row within 4-row group
    const int scol = c0w + ((lane & 15) << 2);

    float apow[kK], vinv[kK], S[kK];
    #pragma unroll
    for (int k = 0; k < kK; ++k) { apow[k] = 1.f; vinv[k] = 1.f; S[k] = 0.f; }

    auto stage = [&](int ch, int bi) {
        #pragma unroll
        for (int q = 0; q < 2; ++q) {
            const float* g = xbase + ((size_t)(ch * kR + q * 4 + roff) * kC + scol);
            __builtin_amdgcn_global_load_lds(
                (const __attribute__((address_space(1))) void*)g,
                (__attribute__((address_space(3))) void*)(&buf[bi][w][q * 4][0]),
                16, 0, 0);
        }
    };

    auto compute = [&](int ch, int bi, bool first) {
        const int tbase = ch * kR;
        #pragma unroll
        for (int i = 0; i < kR; ++i) {
            const float xv = buf[bi][w][i][lane];   // ds_read_b32, conflict-free
            float o = 0.f;
            #pragma unroll
            for (int k = 0; k < kK; ++k) {
                const float wt = (first && i == 0) ? 1.0f : apow[k] * oma[k];
                S[k] = fmaf(xv, wt, S[k]);
                o = fmaf(S[k] * mixw[k], fminf(vinv[k], 1e8f), o);
                apow[k] *= a[k];
                vinv[k] *= inva[k];
            }
            __builtin_nontemporal_store(o, &op[(size_t)(tbase + i) * kC]);
        }
    };

    // ---- prologue: 6 chunks in flight (12 loads) ----
    stage(0, 0); stage(1, 1); stage(2, 2);
    stage(3, 3); stage(4, 4); stage(5, 5);

    // phase k: WAITV(n_k) [retires L_k]; stage(k+6); compute(k)
    // n_k = ops issued after L_k = S_{k-6} + sum over phases k-5..k-1 of
    //       (2 if phase staged) + 8 stores. Prologue-fed phases ramp up.
    WAITV(10); stage( 6, 6); compute(0, 0, true);
    WAITV(18); stage( 7, 7); compute(1, 1, false);
    WAITV(26); stage( 8, 0); compute(2, 2, false);
    WAITV(34); stage( 9, 1); compute(3, 3, false);
    WAITV(42); stage(10, 2); compute(4, 4, false);
    WAITV(50); stage(11, 3); compute(5, 5, false);

    #pragma unroll 1
    for (int k = 6; k <= 35; ++k) {
        WAITV(58);                 // retires L_k; leaves L_{k+1..k+5} + recent stores
        stage(k + 6, (k + 6) & 7);
        compute(k, k & 7, false);
    }

    // tail: no more staging; counts shrink as the load tail drains
    WAITV(58); compute(36, 36 & 7, false);
    WAITV(56); compute(37, 37 & 7, false);
    WAITV(54); compute(38, 38 & 7, false);
    WAITV(52); compute(39, 39 & 7, false);
    WAITV(50); compute(40, 40 & 7, false);
    WAITV(48); compute(41, 41 & 7, false);
}

extern "C" void kernel_launch(void* const* d_in, const int* in_sizes, int n_in,
                              void* d_out, int out_size, void* d_ws, size_t ws_size,
                              hipStream_t stream) {
    const float* x  = (const float*)d_in[0];
    const float* la = (const float*)d_in[1];
    const float* ml = (const float*)d_in[2];
    float* o = (float*)d_out;

    const int blocks = kB * (kC / 256);  // 512 blocks x 256 threads, one thread per (b,c)
    ema_mix_kernel<<<dim3(blocks), dim3(256), 0, stream>>>(x, la, ml, o);
}